// Round 4
// baseline (1073.454 us; speedup 1.0000x reference)
//
#include <hip/hip_runtime.h>
#include <math.h>

#define D_MODEL 512
#define D_FF    2048
#define N_EXP   8
#define N_TOK   8192
#define BM      64

typedef _Float16 half8  __attribute__((ext_vector_type(8)));
typedef float    f32x16 __attribute__((ext_vector_type(16)));

__device__ __forceinline__ void gload_lds16(const void* g, void* lds) {
  __builtin_amdgcn_global_load_lds(
      (const __attribute__((address_space(1))) unsigned int*)g,
      (__attribute__((address_space(3))) unsigned int*)lds, 16, 0, 0);
}

// ---------------- x -> fp16 ----------------
__global__ void cvt_x_kernel(const float* __restrict__ x, _Float16* __restrict__ xb) {
  int i = blockIdx.x * blockDim.x + threadIdx.x;   // 8 elems per thread
  const float4* xp = (const float4*)x + (size_t)i * 2;
  float4 v0 = xp[0], v1 = xp[1];
  half8 o;
  o[0] = (_Float16)v0.x; o[1] = (_Float16)v0.y; o[2] = (_Float16)v0.z; o[3] = (_Float16)v0.w;
  o[4] = (_Float16)v1.x; o[5] = (_Float16)v1.y; o[6] = (_Float16)v1.z; o[7] = (_Float16)v1.w;
  ((half8*)xb)[i] = o;
}

// ---------------- [E][R][C] f32 -> [E][C][R] f16 ----------------
__global__ void transpose_cvt_kernel(const float* __restrict__ in, _Float16* __restrict__ out,
                                     int R, int C) {
  __shared__ float t[32][33];
  int e = blockIdx.z, rb = blockIdx.y, cb = blockIdx.x;
  int tx = threadIdx.x & 31, ty = threadIdx.x >> 5;
  const float* src = in + ((size_t)e * R + rb * 32) * C + cb * 32;
#pragma unroll
  for (int i = 0; i < 32; i += 8) t[ty + i][tx] = src[(size_t)(ty + i) * C + tx];
  __syncthreads();
  _Float16* dst = out + ((size_t)e * C + cb * 32) * R + rb * 32;
#pragma unroll
  for (int i = 0; i < 32; i += 8) dst[(size_t)(ty + i) * R + tx] = (_Float16)t[tx][ty + i];
}

// ---------------- router: softmax(x @ wr + br) ----------------
__global__ void router_kernel(const float* __restrict__ x, const float* __restrict__ wr,
                              const float* __restrict__ br, float* __restrict__ route) {
  int t = (blockIdx.x * blockDim.x + threadIdx.x) >> 6;   // one wave per token
  int lane = threadIdx.x & 63;
  const float4* xp = (const float4*)(x + (size_t)t * D_MODEL) + lane * 2;
  float4 xv0 = xp[0], xv1 = xp[1];
  float xv[8] = {xv0.x, xv0.y, xv0.z, xv0.w, xv1.x, xv1.y, xv1.z, xv1.w};
  float acc[8] = {0, 0, 0, 0, 0, 0, 0, 0};
  int d0 = lane * 8;
#pragma unroll
  for (int i = 0; i < 8; ++i) {
    const float4* wp = (const float4*)(wr + (size_t)(d0 + i) * N_EXP);
    float4 w0 = wp[0], w1v = wp[1];
    acc[0] += xv[i] * w0.x;  acc[1] += xv[i] * w0.y;
    acc[2] += xv[i] * w0.z;  acc[3] += xv[i] * w0.w;
    acc[4] += xv[i] * w1v.x; acc[5] += xv[i] * w1v.y;
    acc[6] += xv[i] * w1v.z; acc[7] += xv[i] * w1v.w;
  }
#pragma unroll
  for (int off = 32; off > 0; off >>= 1)
#pragma unroll
    for (int e2 = 0; e2 < 8; ++e2) acc[e2] += __shfl_xor(acc[e2], off);
  float mx = -1e30f;
#pragma unroll
  for (int e2 = 0; e2 < 8; ++e2) { acc[e2] += br[e2]; mx = fmaxf(mx, acc[e2]); }
  float s = 0.f;
#pragma unroll
  for (int e2 = 0; e2 < 8; ++e2) { acc[e2] = expf(acc[e2] - mx); s += acc[e2]; }
  float inv = 1.f / s;
  if (lane < 8) route[(size_t)t * N_EXP + lane] = acc[lane] * inv;
}

// ---------------- staging: 32KB ring slots ----------------
// w1 slot k8: [128f][128k] f16 — row 256B = 16x16B groups, group g swizzled by f&7.
// w2 slot c : [128d][128f] f16 — row 256B, group g swizzled by d&7.
// gload_lds dest is wave-uniform + lane*16 (linear); src carries the inverse swizzle.
__device__ __forceinline__ void stage_w1(const _Float16* __restrict__ w1t, int e, int f0,
                                         int k8, char* slot, int w, int l) {
#pragma unroll
  for (int i = 0; i < 4; ++i) {
    int n = i * 512 + w * 64 + l;
    int f = n >> 4, g = n & 15;
    int gr = (g & 8) | ((g ^ (f & 7)) & 7);
    gload_lds16(w1t + (size_t)(e * D_FF + f0 + f) * D_MODEL + k8 * 128 + gr * 8,
                slot + (i * 512 + w * 64) * 16);
  }
}
__device__ __forceinline__ void stage_w2(const _Float16* __restrict__ w2t, int e, int f0,
                                         int dq, char* slot, int w, int l) {
#pragma unroll
  for (int i = 0; i < 4; ++i) {
    int n = i * 512 + w * 64 + l;
    int dl = n >> 4, g = n & 15;
    int gr = (g & 8) | ((g ^ (dl & 7)) & 7);
    gload_lds16(w2t + (size_t)(e * D_MODEL + dq * 128 + dl) * D_FF + f0 + gr * 8,
                slot + (i * 512 + w * 64) * 16);
  }
}

// ---------------- fused MoE main (32x32x16 MFMA) ----------------
// 256 blocks (XCD-swizzled: 4 XCDs per expert-group), 512 threads, 1 block/CU.
// Block = 64-token m-tile x 4 experts. Per super-fc (BF=128): 8 phases over a
// 4x32KB ring; stage at phase p -> slot (p+3)&3; vmcnt(8) everywhere (T4).
// GEMM1: wave tile (m: w&1, f: w>>1), A (x) in regs (xfrag[32], 128 VGPR).
// GEMM2: wave tile (m: w&1, d: w>>1 within d-quarter c), A (hs) preloaded
// once per super-fc (a2[8], 32 VGPR), acc[4] f32x16 (64 VGPR).
__global__ __launch_bounds__(512, 2)
void moe_main_kernel(const _Float16* __restrict__ xb, const _Float16* __restrict__ w1t,
                     const _Float16* __restrict__ w2t, const float* __restrict__ b1,
                     const float* __restrict__ b2, const float* __restrict__ route,
                     float* __restrict__ out) {
  __shared__ __align__(16) unsigned char ring[4][32768];   // 128 KB
  __shared__ __align__(16) unsigned char hs[BM * 256];     // 16 KB  [64m][128f]
  __shared__ float routes_lds[4][BM];                      // 1 KB

  const int tid = threadIdx.x;
  const int l   = tid & 63;
  const int w   = tid >> 6;
  const int hl  = l >> 5;         // k-half selector for all 32x32x16 fragments

  // XCD swizzle: xcd = bid&7; XCDs 0-3 -> expert-group 0, 4-7 -> group 1.
  const int bid  = blockIdx.x;
  const int xcd  = bid & 7, slot_in = bid >> 3;
  const int eb   = (xcd >> 2) * 4;
  const int m0   = (slot_in * 4 + (xcd & 3)) * BM;

  const int mh = w & 1;           // m-tile (both GEMMs)
  const int fh = w >> 1;          // GEMM1 f-tile (0..3)
  const int fB = fh * 32 + (l & 31);     // GEMM1 B row (f within super-fc)
  const int mA = mh * 32 + (l & 31);     // GEMM2 A row (m)
  const int dB = (w >> 1) * 32 + (l & 31); // GEMM2 B row (d-local in quarter)

  if (tid < 4 * BM)
    routes_lds[tid >> 6][tid & 63] = route[(size_t)(m0 + (tid & 63)) * N_EXP + eb + (tid >> 6)];
  asm volatile("s_waitcnt lgkmcnt(0)" ::: "memory");

  // x A-fragments: rows m0+mA, k = ks*16 + hl*8 (+0..7), 32 k16-steps = 128 VGPR
  half8 xfrag[32];
  {
    const _Float16* xrow = xb + (size_t)(m0 + mA) * D_MODEL + hl * 8;
#pragma unroll
    for (int ks = 0; ks < 32; ++ks)
      xfrag[ks] = *(const half8*)(xrow + ks * 16);
  }

  f32x16 acc[4];
#pragma unroll
  for (int c = 0; c < 4; ++c)
#pragma unroll
    for (int r = 0; r < 16; ++r) acc[c][r] = 0.f;

  // prologue: stage w1 k8=0,1,2 of (eb, sfc 0)
  stage_w1(w1t, eb, 0, 0, (char*)ring[0], w, l);
  stage_w1(w1t, eb, 0, 1, (char*)ring[1], w, l);
  stage_w1(w1t, eb, 0, 2, (char*)ring[2], w, l);

#pragma unroll 1
  for (int ei = 0; ei < 4; ++ei) {
    const int e = eb + ei;
#pragma unroll 1
    for (int sfc = 0; sfc < 16; ++sfc) {
      const int f0 = sfc * 128;
      int f0N = f0 + 128, eN = e;
      if (f0N == D_FF) { f0N = 0; eN = (ei < 3) ? e + 1 : eb; }  // tail prefetch wraps (harmless)

      float b1v = b1[(size_t)e * D_FF + f0 + fB];

      f32x16 hacc;
#pragma unroll
      for (int r = 0; r < 16; ++r) hacc[r] = 0.f;

      // ---- P0..P3: GEMM1, slot k8 ----
#pragma unroll
      for (int k8 = 0; k8 < 4; ++k8) {
        asm volatile("s_waitcnt vmcnt(8)" ::: "memory");
        __builtin_amdgcn_s_barrier();
        const unsigned char* bb = ring[k8];
        __builtin_amdgcn_s_setprio(1);
#pragma unroll
        for (int kk = 0; kk < 8; ++kk) {
          const int g  = kk * 2 + hl;
          const int sw = (g & 8) | ((g ^ (l & 7)) & 7);
          half8 b = *(const half8*)(bb + fB * 256 + sw * 16);
          hacc = __builtin_amdgcn_mfma_f32_32x32x16_f16(xfrag[k8 * 8 + kk], b, hacc, 0, 0, 0);
        }
        __builtin_amdgcn_s_setprio(0);
        if      (k8 == 0) stage_w1(w1t, e, f0, 3, (char*)ring[3], w, l);
        else if (k8 == 1) stage_w2(w2t, e, f0, 0, (char*)ring[0], w, l);
        else if (k8 == 2) stage_w2(w2t, e, f0, 1, (char*)ring[1], w, l);
        else              stage_w2(w2t, e, f0, 2, (char*)ring[2], w, l);
      }

      // ---- bias + exact gelu + route-scale -> hs ----
#pragma unroll
      for (int r = 0; r < 16; ++r) {
        const int m = mh * 32 + (r & 3) + 8 * (r >> 2) + 4 * hl;
        float v  = hacc[r] + b1v;
        float gl = 0.5f * v * (1.0f + erff(v * 0.70710678118654752f));
        gl *= routes_lds[ei][m];
        const int g  = fh * 4 + ((l & 31) >> 3);
        const int sw = (g & 8) | ((g ^ (m & 7)) & 7);
        *(_Float16*)(hs + m * 256 + sw * 16 + (l & 7) * 2) = (_Float16)gl;
      }
      asm volatile("s_waitcnt lgkmcnt(0)" ::: "memory");

      // ---- P4..P7: GEMM2, slot c ----
      half8 a2[8];
#pragma unroll
      for (int c = 0; c < 4; ++c) {
        asm volatile("s_waitcnt vmcnt(8)" ::: "memory");
        __builtin_amdgcn_s_barrier();
        const unsigned char* bs = ring[c];
        if (c == 0) {   // A-frags from hs, once per super-fc
#pragma unroll
          for (int ks = 0; ks < 8; ++ks) {
            const int g  = ks * 2 + hl;
            const int sw = (g & 8) | ((g ^ (l & 7)) & 7);
            a2[ks] = *(const half8*)(hs + mA * 256 + sw * 16);
          }
        }
        __builtin_amdgcn_s_setprio(1);
#pragma unroll
        for (int ks = 0; ks < 8; ++ks) {
          const int g  = ks * 2 + hl;
          const int sw = (g & 8) | ((g ^ (l & 7)) & 7);
          half8 b = *(const half8*)(bs + dB * 256 + sw * 16);
          acc[c] = __builtin_amdgcn_mfma_f32_32x32x16_f16(a2[ks], b, acc[c], 0, 0, 0);
        }
        __builtin_amdgcn_s_setprio(0);
        if      (c == 0) stage_w2(w2t, e,  f0,  3, (char*)ring[3], w, l);
        else if (c == 1) stage_w1(w1t, eN, f0N, 0, (char*)ring[0], w, l);
        else if (c == 2) stage_w1(w1t, eN, f0N, 1, (char*)ring[1], w, l);
        else             stage_w1(w1t, eN, f0N, 2, (char*)ring[2], w, l);
      }
    }
  }

  asm volatile("s_waitcnt vmcnt(0)" ::: "memory");   // drain tail prefetches

  // ---- epilogue: += sum_e route*b2, then 2-way atomic accumulate ----
#pragma unroll
  for (int c = 0; c < 4; ++c) {
    const int d = c * 128 + (w >> 1) * 32 + (l & 31);
    float b2v[4];
#pragma unroll
    for (int ei = 0; ei < 4; ++ei) b2v[ei] = b2[(size_t)(eb + ei) * D_MODEL + d];
#pragma unroll
    for (int r = 0; r < 16; ++r) {
      const int m = mh * 32 + (r & 3) + 8 * (r >> 2) + 4 * hl;
      float add = 0.f;
#pragma unroll
      for (int ei = 0; ei < 4; ++ei) add += routes_lds[ei][m] * b2v[ei];
      unsafeAtomicAdd(out + (size_t)(m0 + m) * D_MODEL + d, acc[c][r] + add);
    }
  }
}

extern "C" void kernel_launch(void* const* d_in, const int* in_sizes, int n_in,
                              void* d_out, int out_size, void* d_ws, size_t ws_size,
                              hipStream_t stream) {
  (void)in_sizes; (void)n_in; (void)out_size; (void)ws_size;
  const float* x  = (const float*)d_in[0];
  const float* w1 = (const float*)d_in[1];
  const float* b1 = (const float*)d_in[2];
  const float* w2 = (const float*)d_in[3];
  const float* b2 = (const float*)d_in[4];
  const float* wr = (const float*)d_in[5];
  const float* br = (const float*)d_in[6];
  float* out   = (float*)d_out;
  float* route = out + (size_t)N_TOK * D_MODEL;   // output 1 lives in d_out tail

  char* ws = (char*)d_ws;
  _Float16* xb  = (_Float16*)ws;                                           // 8 MiB
  _Float16* w1t = (_Float16*)(ws + (size_t)N_TOK * D_MODEL * 2);           // +16 MiB  [E][F][D]
  _Float16* w2t = (_Float16*)(ws + (size_t)N_TOK * D_MODEL * 2
                                 + (size_t)N_EXP * D_FF * D_MODEL * 2);    // +16 MiB  [E][D][F]

  hipMemsetAsync(out, 0, (size_t)N_TOK * D_MODEL * sizeof(float), stream);
  cvt_x_kernel<<<(N_TOK * D_MODEL / 8) / 256, 256, 0, stream>>>(x, xb);
  transpose_cvt_kernel<<<dim3(D_FF / 32, D_MODEL / 32, N_EXP), 256, 0, stream>>>(w1, w1t, D_MODEL, D_FF);
  transpose_cvt_kernel<<<dim3(D_MODEL / 32, D_FF / 32, N_EXP), 256, 0, stream>>>(w2, w2t, D_FF, D_MODEL);
  router_kernel<<<N_TOK / 4, 256, 0, stream>>>(x, wr, br, route);
  moe_main_kernel<<<256, 512, 0, stream>>>(xb, w1t, w2t, b1, b2, route, out);
}

// Round 5
// 1066.722 us; speedup vs baseline: 1.0063x; 1.0063x over previous
//
#include <hip/hip_runtime.h>
#include <math.h>

#define D_MODEL 512
#define D_FF    2048
#define N_EXP   8
#define N_TOK   8192
#define BM      64

typedef _Float16 half8  __attribute__((ext_vector_type(8)));
typedef float    f32x16 __attribute__((ext_vector_type(16)));

__device__ __forceinline__ void gload_lds16(const void* g, void* lds) {
  __builtin_amdgcn_global_load_lds(
      (const __attribute__((address_space(1))) unsigned int*)g,
      (__attribute__((address_space(3))) unsigned int*)lds, 16, 0, 0);
}

// ---------------- x -> fp16 ----------------
__global__ void cvt_x_kernel(const float* __restrict__ x, _Float16* __restrict__ xb) {
  int i = blockIdx.x * blockDim.x + threadIdx.x;   // 8 elems per thread
  const float4* xp = (const float4*)x + (size_t)i * 2;
  float4 v0 = xp[0], v1 = xp[1];
  half8 o;
  o[0] = (_Float16)v0.x; o[1] = (_Float16)v0.y; o[2] = (_Float16)v0.z; o[3] = (_Float16)v0.w;
  o[4] = (_Float16)v1.x; o[5] = (_Float16)v1.y; o[6] = (_Float16)v1.z; o[7] = (_Float16)v1.w;
  ((half8*)xb)[i] = o;
}

// ---------------- [E][R][C] f32 -> [E][C][R] f16 ----------------
__global__ void transpose_cvt_kernel(const float* __restrict__ in, _Float16* __restrict__ out,
                                     int R, int C) {
  __shared__ float t[32][33];
  int e = blockIdx.z, rb = blockIdx.y, cb = blockIdx.x;
  int tx = threadIdx.x & 31, ty = threadIdx.x >> 5;
  const float* src = in + ((size_t)e * R + rb * 32) * C + cb * 32;
#pragma unroll
  for (int i = 0; i < 32; i += 8) t[ty + i][tx] = src[(size_t)(ty + i) * C + tx];
  __syncthreads();
  _Float16* dst = out + ((size_t)e * C + cb * 32) * R + rb * 32;
#pragma unroll
  for (int i = 0; i < 32; i += 8) dst[(size_t)(ty + i) * R + tx] = (_Float16)t[tx][ty + i];
}

// ---------------- router: softmax(x @ wr + br) ----------------
__global__ void router_kernel(const float* __restrict__ x, const float* __restrict__ wr,
                              const float* __restrict__ br, float* __restrict__ route) {
  int t = (blockIdx.x * blockDim.x + threadIdx.x) >> 6;   // one wave per token
  int lane = threadIdx.x & 63;
  const float4* xp = (const float4*)(x + (size_t)t * D_MODEL) + lane * 2;
  float4 xv0 = xp[0], xv1 = xp[1];
  float xv[8] = {xv0.x, xv0.y, xv0.z, xv0.w, xv1.x, xv1.y, xv1.z, xv1.w};
  float acc[8] = {0, 0, 0, 0, 0, 0, 0, 0};
  int d0 = lane * 8;
#pragma unroll
  for (int i = 0; i < 8; ++i) {
    const float4* wp = (const float4*)(wr + (size_t)(d0 + i) * N_EXP);
    float4 w0 = wp[0], w1v = wp[1];
    acc[0] += xv[i] * w0.x;  acc[1] += xv[i] * w0.y;
    acc[2] += xv[i] * w0.z;  acc[3] += xv[i] * w0.w;
    acc[4] += xv[i] * w1v.x; acc[5] += xv[i] * w1v.y;
    acc[6] += xv[i] * w1v.z; acc[7] += xv[i] * w1v.w;
  }
#pragma unroll
  for (int off = 32; off > 0; off >>= 1)
#pragma unroll
    for (int e2 = 0; e2 < 8; ++e2) acc[e2] += __shfl_xor(acc[e2], off);
  float mx = -1e30f;
#pragma unroll
  for (int e2 = 0; e2 < 8; ++e2) { acc[e2] += br[e2]; mx = fmaxf(mx, acc[e2]); }
  float s = 0.f;
#pragma unroll
  for (int e2 = 0; e2 < 8; ++e2) { acc[e2] = expf(acc[e2] - mx); s += acc[e2]; }
  float inv = 1.f / s;
  if (lane < 8) route[(size_t)t * N_EXP + lane] = acc[lane] * inv;
}

// ---------------- staging: 32KB ring slots ----------------
// w1 slot k8: [128f][128k] f16 — row 256B = 16x16B groups, group g swizzled by f&7.
// w2 slot c : [128d][128f] f16 — row 256B, group g swizzled by d&7.
// gload_lds dest is wave-uniform + lane*16 (linear); src carries the inverse swizzle.
__device__ __forceinline__ void stage_w1(const _Float16* __restrict__ w1t, int e, int f0,
                                         int k8, char* slot, int w, int l) {
#pragma unroll
  for (int i = 0; i < 4; ++i) {
    int n = i * 512 + w * 64 + l;
    int f = n >> 4, g = n & 15;
    int gr = (g & 8) | ((g ^ (f & 7)) & 7);
    gload_lds16(w1t + (size_t)(e * D_FF + f0 + f) * D_MODEL + k8 * 128 + gr * 8,
                slot + (i * 512 + w * 64) * 16);
  }
}
__device__ __forceinline__ void stage_w2(const _Float16* __restrict__ w2t, int e, int f0,
                                         int dq, char* slot, int w, int l) {
#pragma unroll
  for (int i = 0; i < 4; ++i) {
    int n = i * 512 + w * 64 + l;
    int dl = n >> 4, g = n & 15;
    int gr = (g & 8) | ((g ^ (dl & 7)) & 7);
    gload_lds16(w2t + (size_t)(e * D_MODEL + dq * 128 + dl) * D_FF + f0 + gr * 8,
                slot + (i * 512 + w * 64) * 16);
  }
}

// ---------------- fused MoE main (32x32x16 MFMA) ----------------
// grid (128, 2) — EXACT round-3 block->work topology (dispatch-order convoy gave
// 96% L2 hit; round-4's bid&7 remap collapsed it to ~50%: FETCH 150MB->2.2GB).
// Block = 64-token m-tile x 4 experts. Per super-fc (BF=128): 8 phases over a
// 4x32KB ring; stage at phase p -> slot read at p+3; vmcnt(8) everywhere (T4).
// GEMM1: wave tile (m: w&1, f: w>>1), A (x) in regs (xfrag[32], 128 VGPR).
// GEMM2: wave tile (m: w&1, d: w>>1 within d-quarter c), A (hs) preloaded
// once per super-fc (a2[8], 32 VGPR), acc[4] f32x16 (64 AGPR).
__global__ __launch_bounds__(512, 2)
void moe_main_kernel(const _Float16* __restrict__ xb, const _Float16* __restrict__ w1t,
                     const _Float16* __restrict__ w2t, const float* __restrict__ b1,
                     const float* __restrict__ b2, const float* __restrict__ route,
                     float* __restrict__ out) {
  __shared__ __align__(16) unsigned char ring[4][32768];   // 128 KB
  __shared__ __align__(16) unsigned char hs[BM * 256];     // 16 KB  [64m][128f]
  __shared__ float routes_lds[4][BM];                      // 1 KB

  const int tid = threadIdx.x;
  const int l   = tid & 63;
  const int w   = tid >> 6;
  const int hl  = l >> 5;         // k-half selector for all 32x32x16 fragments

  const int eb  = 4 * blockIdx.y;       // round-3 mapping: expert group by gridDim.y
  const int m0  = blockIdx.x * BM;      // m-tile in dispatch order

  const int mh = w & 1;           // m-tile (both GEMMs)
  const int fh = w >> 1;          // GEMM1 f-tile (0..3)
  const int fB = fh * 32 + (l & 31);       // GEMM1 B row (f within super-fc)
  const int mA = mh * 32 + (l & 31);       // GEMM2 A row (m)
  const int dB = (w >> 1) * 32 + (l & 31); // GEMM2 B row (d-local in quarter)

  if (tid < 4 * BM)
    routes_lds[tid >> 6][tid & 63] = route[(size_t)(m0 + (tid & 63)) * N_EXP + eb + (tid >> 6)];
  asm volatile("s_waitcnt lgkmcnt(0)" ::: "memory");

  // x A-fragments: rows m0+mA, k = ks*16 + hl*8 (+0..7), 32 k16-steps = 128 VGPR
  half8 xfrag[32];
  {
    const _Float16* xrow = xb + (size_t)(m0 + mA) * D_MODEL + hl * 8;
#pragma unroll
    for (int ks = 0; ks < 32; ++ks)
      xfrag[ks] = *(const half8*)(xrow + ks * 16);
  }

  f32x16 acc[4];
#pragma unroll
  for (int c = 0; c < 4; ++c)
#pragma unroll
    for (int r = 0; r < 16; ++r) acc[c][r] = 0.f;

  // prologue: stage w1 k8=0,1,2 of (eb, sfc 0)
  stage_w1(w1t, eb, 0, 0, (char*)ring[0], w, l);
  stage_w1(w1t, eb, 0, 1, (char*)ring[1], w, l);
  stage_w1(w1t, eb, 0, 2, (char*)ring[2], w, l);

#pragma unroll 1
  for (int ei = 0; ei < 4; ++ei) {
    const int e = eb + ei;
#pragma unroll 1
    for (int sfc = 0; sfc < 16; ++sfc) {
      const int f0 = sfc * 128;
      int f0N = f0 + 128, eN = e;
      if (f0N == D_FF) { f0N = 0; eN = (ei < 3) ? e + 1 : eb; }  // tail prefetch wraps (harmless)

      float b1v = b1[(size_t)e * D_FF + f0 + fB];

      f32x16 hacc;
#pragma unroll
      for (int r = 0; r < 16; ++r) hacc[r] = 0.f;

      // ---- P0..P3: GEMM1, slot k8 ----
#pragma unroll
      for (int k8 = 0; k8 < 4; ++k8) {
        asm volatile("s_waitcnt vmcnt(8)" ::: "memory");
        __builtin_amdgcn_s_barrier();
        const unsigned char* bb = ring[k8];
        __builtin_amdgcn_s_setprio(1);
#pragma unroll
        for (int kk = 0; kk < 8; ++kk) {
          const int g  = kk * 2 + hl;
          const int sw = (g & 8) | ((g ^ (l & 7)) & 7);
          half8 b = *(const half8*)(bb + fB * 256 + sw * 16);
          hacc = __builtin_amdgcn_mfma_f32_32x32x16_f16(xfrag[k8 * 8 + kk], b, hacc, 0, 0, 0);
        }
        __builtin_amdgcn_s_setprio(0);
        if      (k8 == 0) stage_w1(w1t, e, f0, 3, (char*)ring[3], w, l);
        else if (k8 == 1) stage_w2(w2t, e, f0, 0, (char*)ring[0], w, l);
        else if (k8 == 2) stage_w2(w2t, e, f0, 1, (char*)ring[1], w, l);
        else              stage_w2(w2t, e, f0, 2, (char*)ring[2], w, l);
      }

      // ---- bias + exact gelu + route-scale -> hs ----
#pragma unroll
      for (int r = 0; r < 16; ++r) {
        const int m = mh * 32 + (r & 3) + 8 * (r >> 2) + 4 * hl;
        float v  = hacc[r] + b1v;
        float gl = 0.5f * v * (1.0f + erff(v * 0.70710678118654752f));
        gl *= routes_lds[ei][m];
        const int g  = fh * 4 + ((l & 31) >> 3);
        const int sw = (g & 8) | ((g ^ (m & 7)) & 7);
        *(_Float16*)(hs + m * 256 + sw * 16 + (l & 7) * 2) = (_Float16)gl;
      }
      asm volatile("s_waitcnt lgkmcnt(0)" ::: "memory");

      // ---- P4..P7: GEMM2, slot c ----
      half8 a2[8];
#pragma unroll
      for (int c = 0; c < 4; ++c) {
        asm volatile("s_waitcnt vmcnt(8)" ::: "memory");
        __builtin_amdgcn_s_barrier();
        const unsigned char* bs = ring[c];
        if (c == 0) {   // A-frags from hs, once per super-fc
#pragma unroll
          for (int ks = 0; ks < 8; ++ks) {
            const int g  = ks * 2 + hl;
            const int sw = (g & 8) | ((g ^ (l & 7)) & 7);
            a2[ks] = *(const half8*)(hs + mA * 256 + sw * 16);
          }
        }
        __builtin_amdgcn_s_setprio(1);
#pragma unroll
        for (int ks = 0; ks < 8; ++ks) {
          const int g  = ks * 2 + hl;
          const int sw = (g & 8) | ((g ^ (l & 7)) & 7);
          half8 b = *(const half8*)(bs + dB * 256 + sw * 16);
          acc[c] = __builtin_amdgcn_mfma_f32_32x32x16_f16(a2[ks], b, acc[c], 0, 0, 0);
        }
        __builtin_amdgcn_s_setprio(0);
        if      (c == 0) stage_w2(w2t, e,  f0,  3, (char*)ring[3], w, l);
        else if (c == 1) stage_w1(w1t, eN, f0N, 0, (char*)ring[0], w, l);
        else if (c == 2) stage_w1(w1t, eN, f0N, 1, (char*)ring[1], w, l);
        else             stage_w1(w1t, eN, f0N, 2, (char*)ring[2], w, l);
      }
    }
  }

  asm volatile("s_waitcnt vmcnt(0)" ::: "memory");   // drain tail prefetches

  // ---- epilogue: += sum_e route*b2, then 2-way atomic accumulate ----
#pragma unroll
  for (int c = 0; c < 4; ++c) {
    const int d = c * 128 + (w >> 1) * 32 + (l & 31);
    float b2v[4];
#pragma unroll
    for (int ei = 0; ei < 4; ++ei) b2v[ei] = b2[(size_t)(eb + ei) * D_MODEL + d];
#pragma unroll
    for (int r = 0; r < 16; ++r) {
      const int m = mh * 32 + (r & 3) + 8 * (r >> 2) + 4 * hl;
      float add = 0.f;
#pragma unroll
      for (int ei = 0; ei < 4; ++ei) add += routes_lds[ei][m] * b2v[ei];
      unsafeAtomicAdd(out + (size_t)(m0 + m) * D_MODEL + d, acc[c][r] + add);
    }
  }
}

extern "C" void kernel_launch(void* const* d_in, const int* in_sizes, int n_in,
                              void* d_out, int out_size, void* d_ws, size_t ws_size,
                              hipStream_t stream) {
  (void)in_sizes; (void)n_in; (void)out_size; (void)ws_size;
  const float* x  = (const float*)d_in[0];
  const float* w1 = (const float*)d_in[1];
  const float* b1 = (const float*)d_in[2];
  const float* w2 = (const float*)d_in[3];
  const float* b2 = (const float*)d_in[4];
  const float* wr = (const float*)d_in[5];
  const float* br = (const float*)d_in[6];
  float* out   = (float*)d_out;
  float* route = out + (size_t)N_TOK * D_MODEL;   // output 1 lives in d_out tail

  char* ws = (char*)d_ws;
  _Float16* xb  = (_Float16*)ws;                                           // 8 MiB
  _Float16* w1t = (_Float16*)(ws + (size_t)N_TOK * D_MODEL * 2);           // +16 MiB  [E][F][D]
  _Float16* w2t = (_Float16*)(ws + (size_t)N_TOK * D_MODEL * 2
                                 + (size_t)N_EXP * D_FF * D_MODEL * 2);    // +16 MiB  [E][D][F]

  hipMemsetAsync(out, 0, (size_t)N_TOK * D_MODEL * sizeof(float), stream);
  cvt_x_kernel<<<(N_TOK * D_MODEL / 8) / 256, 256, 0, stream>>>(x, xb);
  transpose_cvt_kernel<<<dim3(D_FF / 32, D_MODEL / 32, N_EXP), 256, 0, stream>>>(w1, w1t, D_MODEL, D_FF);
  transpose_cvt_kernel<<<dim3(D_MODEL / 32, D_FF / 32, N_EXP), 256, 0, stream>>>(w2, w2t, D_FF, D_MODEL);
  router_kernel<<<N_TOK / 4, 256, 0, stream>>>(x, wr, br, route);
  moe_main_kernel<<<dim3(N_TOK / BM, 2), 512, 0, stream>>>(xb, w1t, w2t, b1, b2, route, out);
}

// Round 6
// 684.084 us; speedup vs baseline: 1.5692x; 1.5593x over previous
//
#include <hip/hip_runtime.h>
#include <math.h>

#define D_MODEL 512
#define D_FF    2048
#define N_EXP   8
#define N_TOK   8192
#define BM      64
#define BF      64

typedef _Float16 half8 __attribute__((ext_vector_type(8)));
typedef float    f32x4 __attribute__((ext_vector_type(4)));

__device__ __forceinline__ void gload_lds16(const void* g, void* lds) {
  __builtin_amdgcn_global_load_lds(
      (const __attribute__((address_space(1))) unsigned int*)g,
      (__attribute__((address_space(3))) unsigned int*)lds, 16, 0, 0);
}

// ---------------- x -> fp16 ----------------
__global__ void cvt_x_kernel(const float* __restrict__ x, _Float16* __restrict__ xb) {
  int i = blockIdx.x * blockDim.x + threadIdx.x;   // 8 elems per thread
  const float4* xp = (const float4*)x + (size_t)i * 2;
  float4 v0 = xp[0], v1 = xp[1];
  half8 o;
  o[0] = (_Float16)v0.x; o[1] = (_Float16)v0.y; o[2] = (_Float16)v0.z; o[3] = (_Float16)v0.w;
  o[4] = (_Float16)v1.x; o[5] = (_Float16)v1.y; o[6] = (_Float16)v1.z; o[7] = (_Float16)v1.w;
  ((half8*)xb)[i] = o;
}

// ---------------- [E][R][C] f32 -> [E][C][R] f16 ----------------
__global__ void transpose_cvt_kernel(const float* __restrict__ in, _Float16* __restrict__ out,
                                     int R, int C) {
  __shared__ float t[32][33];
  int e = blockIdx.z, rb = blockIdx.y, cb = blockIdx.x;
  int tx = threadIdx.x & 31, ty = threadIdx.x >> 5;
  const float* src = in + ((size_t)e * R + rb * 32) * C + cb * 32;
#pragma unroll
  for (int i = 0; i < 32; i += 8) t[ty + i][tx] = src[(size_t)(ty + i) * C + tx];
  __syncthreads();
  _Float16* dst = out + ((size_t)e * C + cb * 32) * R + rb * 32;
#pragma unroll
  for (int i = 0; i < 32; i += 8) dst[(size_t)(ty + i) * R + tx] = (_Float16)t[tx][ty + i];
}

// ---------------- router: softmax(x @ wr + br) ----------------
__global__ void router_kernel(const float* __restrict__ x, const float* __restrict__ wr,
                              const float* __restrict__ br, float* __restrict__ route) {
  int t = (blockIdx.x * blockDim.x + threadIdx.x) >> 6;   // one wave per token
  int lane = threadIdx.x & 63;
  const float4* xp = (const float4*)(x + (size_t)t * D_MODEL) + lane * 2;
  float4 xv0 = xp[0], xv1 = xp[1];
  float xv[8] = {xv0.x, xv0.y, xv0.z, xv0.w, xv1.x, xv1.y, xv1.z, xv1.w};
  float acc[8] = {0, 0, 0, 0, 0, 0, 0, 0};
  int d0 = lane * 8;
#pragma unroll
  for (int i = 0; i < 8; ++i) {
    const float4* wp = (const float4*)(wr + (size_t)(d0 + i) * N_EXP);
    float4 w0 = wp[0], w1v = wp[1];
    acc[0] += xv[i] * w0.x;  acc[1] += xv[i] * w0.y;
    acc[2] += xv[i] * w0.z;  acc[3] += xv[i] * w0.w;
    acc[4] += xv[i] * w1v.x; acc[5] += xv[i] * w1v.y;
    acc[6] += xv[i] * w1v.z; acc[7] += xv[i] * w1v.w;
  }
#pragma unroll
  for (int off = 32; off > 0; off >>= 1)
#pragma unroll
    for (int e2 = 0; e2 < 8; ++e2) acc[e2] += __shfl_xor(acc[e2], off);
  float mx = -1e30f;
#pragma unroll
  for (int e2 = 0; e2 < 8; ++e2) { acc[e2] += br[e2]; mx = fmaxf(mx, acc[e2]); }
  float s = 0.f;
#pragma unroll
  for (int e2 = 0; e2 < 8; ++e2) { acc[e2] = expf(acc[e2] - mx); s += acc[e2]; }
  float inv = 1.f / s;
  if (lane < 8) route[(size_t)t * N_EXP + lane] = acc[lane] * inv;
}

// ---------------- staging: full 64KB fc-panels ----------------
// slotA: w1 panel [64f][512k] f16, row 1024B = 64 x 16B chunks; chunk s holds
//        k-group s' = (s & ~7) | ((s ^ f) & 7)  (XOR involution within 128B oct).
// slotB: w2 panel [512d][64f] f16, row 128B = 8 chunks; chunk s holds f-group s ^ (d&7).
// gload_lds dest = wave-uniform base + lane*16 (linear); source carries the inverse swizzle.
__device__ __forceinline__ void stage_w1_panel(const _Float16* __restrict__ w1t, int e, int f0,
                                               char* slotA, int w, int l) {
#pragma unroll
  for (int i = 0; i < 8; ++i) {
    const int f  = i * 8 + w;                       // one row per instruction
    const int sp = (l & ~7) | ((l ^ f) & 7);        // source chunk for LDS chunk l
    gload_lds16(w1t + ((size_t)e * D_FF + f0 + f) * D_MODEL + sp * 8,
                slotA + f * 1024);
  }
}
__device__ __forceinline__ void stage_w2_panel(const _Float16* __restrict__ w2t, int e, int f0,
                                               char* slotB, int w, int l) {
#pragma unroll
  for (int i = 0; i < 8; ++i) {
    const int d0r = (i * 8 + w) * 8;                // 8 rows per instruction
    const int d   = d0r + (l >> 3);
    const int sp  = (l & 7) ^ (d & 7);              // source f-group for LDS chunk (l&7)
    gload_lds16(w2t + ((size_t)e * D_MODEL + d) * D_FF + f0 + sp * 8,
                slotB + d0r * 128);
  }
}

// ---------------- fused MoE main (2 mega-phases per fc) ----------------
// grid (128, 2) — r3's exact block->work topology (convoy-verified: FETCH 150MB).
// Block = 64-token m-tile x 4 experts, 512 threads (8 waves), 1 block/CU.
// Per fc: G1 {vmcnt(8), barrier, 16 ds_read + 32 MFMA, barrier, stage w1-next,
// gelu->hs, lgkmcnt(0)}; G2 {vmcnt(8), barrier, 16 ds_read + 32 MFMA, barrier,
// stage w2-next}. Counted vmcnt: next panel's 8 loads always in flight (T4).
// GEMM1: waves (m: w&1 -> 32 rows, f: w>>1 -> 16 cols), A(x) in regs xfrag[2][16].
// GEMM2: waves (d: w -> 64 cols, all 64 m), A(hs) a2[4][2], acc[4][4] f32x4.
__global__ __launch_bounds__(512, 2)
void moe_main_kernel(const _Float16* __restrict__ xb, const _Float16* __restrict__ w1t,
                     const _Float16* __restrict__ w2t, const float* __restrict__ b1,
                     const float* __restrict__ b2, const float* __restrict__ route,
                     float* __restrict__ out) {
  __shared__ __align__(16) unsigned char slotA[BF * D_MODEL * 2];   // 64 KB w1 panel
  __shared__ __align__(16) unsigned char slotB[D_MODEL * BF * 2];   // 64 KB w2 panel
  __shared__ __align__(16) unsigned char hs[BM * BF * 2];           // 8 KB [64m][64f]
  __shared__ float routes_lds[4][BM];                               // 1 KB

  const int tid = threadIdx.x;
  const int l   = tid & 63;
  const int w   = tid >> 6;
  const int eb  = 4 * blockIdx.y;
  const int m0  = blockIdx.x * BM;

  const int mh = w & 1;                    // GEMM1 m-half (32 rows)
  const int fq = w >> 1;                   // GEMM1 f-tile (16 cols)
  const int fB = fq * 16 + (l & 15);       // GEMM1 B row (f)
  const int dq = w;                        // GEMM2 d-group (64 cols)

  if (tid < 4 * BM)
    routes_lds[tid >> 6][tid & 63] = route[(size_t)(m0 + (tid & 63)) * N_EXP + eb + (tid >> 6)];
  asm volatile("s_waitcnt lgkmcnt(0)" ::: "memory");

  // x A-fragments in registers: rows m0 + 32*mh + 16*mi + (l&15), K=512 (128 VGPR)
  half8 xfrag[2][16];
#pragma unroll
  for (int mi = 0; mi < 2; ++mi) {
    const _Float16* xrow = xb + (size_t)(m0 + 32 * mh + 16 * mi + (l & 15)) * D_MODEL + (l >> 4) * 8;
#pragma unroll
    for (int ks = 0; ks < 16; ++ks)
      xfrag[mi][ks] = *(const half8*)(xrow + ks * 32);
  }

  f32x4 acc[4][4];
#pragma unroll
  for (int a = 0; a < 4; ++a)
#pragma unroll
    for (int b = 0; b < 4; ++b) acc[a][b] = (f32x4){0.f, 0.f, 0.f, 0.f};

  // prologue: both panels of (eb, fc=0)
  stage_w1_panel(w1t, eb, 0, (char*)slotA, w, l);
  stage_w2_panel(w2t, eb, 0, (char*)slotB, w, l);

#pragma unroll 1
  for (int ei = 0; ei < 4; ++ei) {
    const int e = eb + ei;
#pragma unroll 1
    for (int fc = 0; fc < 32; ++fc) {
      const int f0 = fc * BF;
      int f0N = f0 + BF, eN = e;
      if (f0N == D_FF) { f0N = 0; eN = (ei < 3) ? e + 1 : eb; }   // tail prefetch wraps (harmless)

      float b1v = b1[(size_t)e * D_FF + f0 + fB];

      // ---- G1: h = x @ w1-panel, full K=512 ----
      asm volatile("s_waitcnt vmcnt(8)" ::: "memory");  // w1 panel landed (w2 panel in flight)
      __builtin_amdgcn_s_barrier();
      f32x4 hacc[2];
      hacc[0] = (f32x4){0.f, 0.f, 0.f, 0.f};
      hacc[1] = (f32x4){0.f, 0.f, 0.f, 0.f};
      __builtin_amdgcn_s_setprio(1);
#pragma unroll
      for (int kh = 0; kh < 16; ++kh) {
        const int g = kh * 4 + (l >> 4);
        const int s = (g & ~7) | ((g ^ fB) & 7);
        half8 b = *(const half8*)(slotA + fB * 1024 + s * 16);
        hacc[0] = __builtin_amdgcn_mfma_f32_16x16x32_f16(xfrag[0][kh], b, hacc[0], 0, 0, 0);
        hacc[1] = __builtin_amdgcn_mfma_f32_16x16x32_f16(xfrag[1][kh], b, hacc[1], 0, 0, 0);
      }
      __builtin_amdgcn_s_setprio(0);
      __builtin_amdgcn_s_barrier();                     // all waves done reading slotA
      stage_w1_panel(w1t, eN, f0N, (char*)slotA, w, l); // next w1 panel (8 loads, overlaps gelu)

      // ---- bias + exact gelu + route-scale -> hs ----
#pragma unroll
      for (int mi = 0; mi < 2; ++mi) {
#pragma unroll
        for (int r = 0; r < 4; ++r) {
          const int m = 32 * mh + 16 * mi + (l >> 4) * 4 + r;
          float v  = hacc[mi][r] + b1v;
          float gl = 0.5f * v * (1.0f + erff(v * 0.70710678118654752f));
          gl *= routes_lds[ei][m];
          const int sh = (fB >> 3) ^ (m & 7);
          *(_Float16*)(hs + m * 128 + sh * 16 + (fB & 7) * 2) = (_Float16)gl;
        }
      }
      asm volatile("s_waitcnt lgkmcnt(0)" ::: "memory");  // hs writes done before barrier

      // ---- G2: out += gelu(h) @ w2-panel ----
      asm volatile("s_waitcnt vmcnt(8)" ::: "memory");  // w2 panel landed (w1-next in flight)
      __builtin_amdgcn_s_barrier();                     // also publishes hs
      __builtin_amdgcn_s_setprio(1);
      half8 a2[4][2];
#pragma unroll
      for (int mi = 0; mi < 4; ++mi)
#pragma unroll
        for (int kh = 0; kh < 2; ++kh) {
          const int mr = 16 * mi + (l & 15);
          const int sh = (kh * 4 + (l >> 4)) ^ (mr & 7);
          a2[mi][kh] = *(const half8*)(hs + mr * 128 + sh * 16);
        }
#pragma unroll
      for (int kh = 0; kh < 2; ++kh)
#pragma unroll
        for (int jn = 0; jn < 4; ++jn) {
          const int dB = 64 * dq + 16 * jn + (l & 15);
          const int s  = (kh * 4 + (l >> 4)) ^ (dB & 7);
          half8 b = *(const half8*)(slotB + dB * 128 + s * 16);
#pragma unroll
          for (int mi = 0; mi < 4; ++mi)
            acc[mi][jn] = __builtin_amdgcn_mfma_f32_16x16x32_f16(a2[mi][kh], b, acc[mi][jn], 0, 0, 0);
        }
      __builtin_amdgcn_s_setprio(0);
      __builtin_amdgcn_s_barrier();                     // all waves done reading slotB
      stage_w2_panel(w2t, eN, f0N, (char*)slotB, w, l); // next w2 panel
    }
  }

  asm volatile("s_waitcnt vmcnt(0)" ::: "memory");      // drain tail prefetches

  // ---- epilogue: += sum_e route*b2, then 2-way atomic accumulate ----
#pragma unroll
  for (int jn = 0; jn < 4; ++jn) {
    const int dcol = 64 * dq + 16 * jn + (l & 15);
    float b2v[4];
#pragma unroll
    for (int ei = 0; ei < 4; ++ei) b2v[ei] = b2[(size_t)(eb + ei) * D_MODEL + dcol];
#pragma unroll
    for (int mi = 0; mi < 4; ++mi)
#pragma unroll
      for (int r = 0; r < 4; ++r) {
        const int m = 16 * mi + (l >> 4) * 4 + r;
        float add = 0.f;
#pragma unroll
        for (int ei = 0; ei < 4; ++ei) add += routes_lds[ei][m] * b2v[ei];
        unsafeAtomicAdd(out + (size_t)(m0 + m) * D_MODEL + dcol, acc[mi][jn][r] + add);
      }
  }
}

extern "C" void kernel_launch(void* const* d_in, const int* in_sizes, int n_in,
                              void* d_out, int out_size, void* d_ws, size_t ws_size,
                              hipStream_t stream) {
  (void)in_sizes; (void)n_in; (void)out_size; (void)ws_size;
  const float* x  = (const float*)d_in[0];
  const float* w1 = (const float*)d_in[1];
  const float* b1 = (const float*)d_in[2];
  const float* w2 = (const float*)d_in[3];
  const float* b2 = (const float*)d_in[4];
  const float* wr = (const float*)d_in[5];
  const float* br = (const float*)d_in[6];
  float* out   = (float*)d_out;
  float* route = out + (size_t)N_TOK * D_MODEL;   // output 1 lives in d_out tail

  char* ws = (char*)d_ws;
  _Float16* xb  = (_Float16*)ws;                                           // 8 MiB
  _Float16* w1t = (_Float16*)(ws + (size_t)N_TOK * D_MODEL * 2);           // +16 MiB  [E][F][D]
  _Float16* w2t = (_Float16*)(ws + (size_t)N_TOK * D_MODEL * 2
                                 + (size_t)N_EXP * D_FF * D_MODEL * 2);    // +16 MiB  [E][D][F]

  hipMemsetAsync(out, 0, (size_t)N_TOK * D_MODEL * sizeof(float), stream);
  cvt_x_kernel<<<(N_TOK * D_MODEL / 8) / 256, 256, 0, stream>>>(x, xb);
  transpose_cvt_kernel<<<dim3(D_FF / 32, D_MODEL / 32, N_EXP), 256, 0, stream>>>(w1, w1t, D_MODEL, D_FF);
  transpose_cvt_kernel<<<dim3(D_MODEL / 32, D_FF / 32, N_EXP), 256, 0, stream>>>(w2, w2t, D_FF, D_MODEL);
  router_kernel<<<N_TOK / 4, 256, 0, stream>>>(x, wr, br, route);
  moe_main_kernel<<<dim3(N_TOK / BM, 2), 512, 0, stream>>>(xb, w1t, w2t, b1, b2, route, out);
}

// Round 7
// 577.170 us; speedup vs baseline: 1.8599x; 1.1852x over previous
//
#include <hip/hip_runtime.h>
#include <math.h>

#define D_MODEL 512
#define D_FF    2048
#define N_EXP   8
#define N_TOK   8192
#define BM      64
#define BF      64

typedef _Float16 half8 __attribute__((ext_vector_type(8)));
typedef float    f32x4 __attribute__((ext_vector_type(4)));

__device__ __forceinline__ void gload_lds16(const void* g, void* lds) {
  __builtin_amdgcn_global_load_lds(
      (const __attribute__((address_space(1))) unsigned int*)g,
      (__attribute__((address_space(3))) unsigned int*)lds, 16, 0, 0);
}

// ---------------- x -> fp16 ----------------
__global__ void cvt_x_kernel(const float* __restrict__ x, _Float16* __restrict__ xb) {
  int i = blockIdx.x * blockDim.x + threadIdx.x;   // 8 elems per thread
  const float4* xp = (const float4*)x + (size_t)i * 2;
  float4 v0 = xp[0], v1 = xp[1];
  half8 o;
  o[0] = (_Float16)v0.x; o[1] = (_Float16)v0.y; o[2] = (_Float16)v0.z; o[3] = (_Float16)v0.w;
  o[4] = (_Float16)v1.x; o[5] = (_Float16)v1.y; o[6] = (_Float16)v1.z; o[7] = (_Float16)v1.w;
  ((half8*)xb)[i] = o;
}

// ---------------- [E][R][C] f32 -> [E][C][R] f16 ----------------
__global__ void transpose_cvt_kernel(const float* __restrict__ in, _Float16* __restrict__ out,
                                     int R, int C) {
  __shared__ float t[32][33];
  int e = blockIdx.z, rb = blockIdx.y, cb = blockIdx.x;
  int tx = threadIdx.x & 31, ty = threadIdx.x >> 5;
  const float* src = in + ((size_t)e * R + rb * 32) * C + cb * 32;
#pragma unroll
  for (int i = 0; i < 32; i += 8) t[ty + i][tx] = src[(size_t)(ty + i) * C + tx];
  __syncthreads();
  _Float16* dst = out + ((size_t)e * C + cb * 32) * R + rb * 32;
#pragma unroll
  for (int i = 0; i < 32; i += 8) dst[(size_t)(ty + i) * R + tx] = (_Float16)t[tx][ty + i];
}

// ---------------- router: softmax(x @ wr + br) ----------------
__global__ void router_kernel(const float* __restrict__ x, const float* __restrict__ wr,
                              const float* __restrict__ br, float* __restrict__ route) {
  int t = (blockIdx.x * blockDim.x + threadIdx.x) >> 6;   // one wave per token
  int lane = threadIdx.x & 63;
  const float4* xp = (const float4*)(x + (size_t)t * D_MODEL) + lane * 2;
  float4 xv0 = xp[0], xv1 = xp[1];
  float xv[8] = {xv0.x, xv0.y, xv0.z, xv0.w, xv1.x, xv1.y, xv1.z, xv1.w};
  float acc[8] = {0, 0, 0, 0, 0, 0, 0, 0};
  int d0 = lane * 8;
#pragma unroll
  for (int i = 0; i < 8; ++i) {
    const float4* wp = (const float4*)(wr + (size_t)(d0 + i) * N_EXP);
    float4 w0 = wp[0], w1v = wp[1];
    acc[0] += xv[i] * w0.x;  acc[1] += xv[i] * w0.y;
    acc[2] += xv[i] * w0.z;  acc[3] += xv[i] * w0.w;
    acc[4] += xv[i] * w1v.x; acc[5] += xv[i] * w1v.y;
    acc[6] += xv[i] * w1v.z; acc[7] += xv[i] * w1v.w;
  }
#pragma unroll
  for (int off = 32; off > 0; off >>= 1)
#pragma unroll
    for (int e2 = 0; e2 < 8; ++e2) acc[e2] += __shfl_xor(acc[e2], off);
  float mx = -1e30f;
#pragma unroll
  for (int e2 = 0; e2 < 8; ++e2) { acc[e2] += br[e2]; mx = fmaxf(mx, acc[e2]); }
  float s = 0.f;
#pragma unroll
  for (int e2 = 0; e2 < 8; ++e2) { acc[e2] = expf(acc[e2] - mx); s += acc[e2]; }
  float inv = 1.f / s;
  if (lane < 8) route[(size_t)t * N_EXP + lane] = acc[lane] * inv;
}

// ---------------- staging: full 64KB fc-panels ----------------
// slotA: w1 panel [64f][512k] f16, row 1024B = 64 x 16B chunks; chunk s holds
//        k-group s' = (s & ~7) | ((s ^ f) & 7)  (XOR involution within 128B oct).
// slotB: w2 panel [512d][64f] f16, row 128B = 8 chunks; chunk s holds f-group s ^ (d&7).
// gload_lds dest = wave-uniform base + lane*16 (linear); source carries the inverse swizzle.
__device__ __forceinline__ void stage_w1_panel(const _Float16* __restrict__ w1t, int e, int f0,
                                               char* slotA, int w, int l) {
#pragma unroll
  for (int i = 0; i < 8; ++i) {
    const int f  = i * 8 + w;                       // one row per instruction
    const int sp = (l & ~7) | ((l ^ f) & 7);        // source chunk for LDS chunk l
    gload_lds16(w1t + ((size_t)e * D_FF + f0 + f) * D_MODEL + sp * 8,
                slotA + f * 1024);
  }
}
__device__ __forceinline__ void stage_w2_panel(const _Float16* __restrict__ w2t, int e, int f0,
                                               char* slotB, int w, int l) {
#pragma unroll
  for (int i = 0; i < 8; ++i) {
    const int d0r = (i * 8 + w) * 8;                // 8 rows per instruction
    const int d   = d0r + (l >> 3);
    const int sp  = (l & 7) ^ (d & 7);              // source f-group for LDS chunk (l&7)
    gload_lds16(w2t + ((size_t)e * D_MODEL + d) * D_FF + f0 + sp * 8,
                slotB + d0r * 128);
  }
}

// ---------------- fused MoE main (2 mega-phases per fc) ----------------
// grid (128, 2) — convoy-verified block->work topology (FETCH ~146MB).
// Per fc: G1 {vmcnt(8)=w1-panel, barrier, 16 ds_read + 32 MFMA, barrier,
// stage w1-next}; gelu (tanh form, b1 from LDS, NO vmem) -> hs (rsw swizzle);
// G2 {vmcnt(8)=w2-panel, barrier, reads + 32 MFMA, barrier, stage w2-next}.
// vmcnt discipline: each wait drains exactly the 8 loads of the panel needed.
__global__ __launch_bounds__(512, 2)
void moe_main_kernel(const _Float16* __restrict__ xb, const _Float16* __restrict__ w1t,
                     const _Float16* __restrict__ w2t, const float* __restrict__ b1,
                     const float* __restrict__ b2, const float* __restrict__ route,
                     float* __restrict__ out) {
  __shared__ __align__(16) unsigned char slotA[BF * D_MODEL * 2];   // 64 KB w1 panel
  __shared__ __align__(16) unsigned char slotB[D_MODEL * BF * 2];   // 64 KB w2 panel
  __shared__ __align__(16) unsigned char hs[BM * BF * 2];           // 8 KB [64m][64f]
  __shared__ _Float16 b1_lds[4 * D_FF];                             // 16 KB
  __shared__ float routes_lds[4][BM];                               // 1 KB

  const int tid = threadIdx.x;
  const int l   = tid & 63;
  const int w   = tid >> 6;
  const int eb  = 4 * blockIdx.y;
  const int m0  = blockIdx.x * BM;

  const int mh = w & 1;                    // GEMM1 m-half (32 rows)
  const int fq = w >> 1;                   // GEMM1 f-tile (16 cols)
  const int fB = fq * 16 + (l & 15);       // GEMM1 B row (f)
  const int dq = w;                        // GEMM2 d-group (64 cols)

  // stage b1 (4 experts, f16) + routes to LDS
#pragma unroll
  for (int i = 0; i < 16; ++i) {
    int idx = i * 512 + tid;
    int ee = idx >> 11, ff = idx & 2047;
    b1_lds[idx] = (_Float16)b1[(size_t)(eb + ee) * D_FF + ff];
  }
  if (tid < 4 * BM)
    routes_lds[tid >> 6][tid & 63] = route[(size_t)(m0 + (tid & 63)) * N_EXP + eb + (tid >> 6)];
  asm volatile("s_waitcnt lgkmcnt(0)" ::: "memory");

  // x A-fragments in registers: rows m0 + 32*mh + 16*mi + (l&15), K=512 (128 VGPR)
  half8 xfrag[2][16];
#pragma unroll
  for (int mi = 0; mi < 2; ++mi) {
    const _Float16* xrow = xb + (size_t)(m0 + 32 * mh + 16 * mi + (l & 15)) * D_MODEL + (l >> 4) * 8;
#pragma unroll
    for (int ks = 0; ks < 16; ++ks)
      xfrag[mi][ks] = *(const half8*)(xrow + ks * 32);
  }

  f32x4 acc[4][4];
#pragma unroll
  for (int a = 0; a < 4; ++a)
#pragma unroll
    for (int b = 0; b < 4; ++b) acc[a][b] = (f32x4){0.f, 0.f, 0.f, 0.f};

  // prologue: both panels of (eb, fc=0)
  stage_w1_panel(w1t, eb, 0, (char*)slotA, w, l);
  stage_w2_panel(w2t, eb, 0, (char*)slotB, w, l);

#pragma unroll 1
  for (int ei = 0; ei < 4; ++ei) {
    const int e = eb + ei;
#pragma unroll 1
    for (int fc = 0; fc < 32; ++fc) {
      const int f0 = fc * BF;
      int f0N = f0 + BF, eN = e;
      if (f0N == D_FF) { f0N = 0; eN = (ei < 3) ? e + 1 : eb; }   // tail prefetch wraps (harmless)

      float b1v = (float)b1_lds[ei * D_FF + f0 + fB];             // LDS, no vmcnt coupling

      // ---- G1: h = x @ w1-panel, full K=512 ----
      asm volatile("s_waitcnt vmcnt(8)" ::: "memory");  // w1 panel landed (w2 panel in flight)
      __builtin_amdgcn_s_barrier();
      f32x4 hacc[2];
      hacc[0] = (f32x4){0.f, 0.f, 0.f, 0.f};
      hacc[1] = (f32x4){0.f, 0.f, 0.f, 0.f};
      __builtin_amdgcn_s_setprio(1);
#pragma unroll
      for (int kh = 0; kh < 16; ++kh) {
        const int g = kh * 4 + (l >> 4);
        const int s = (g & ~7) | ((g ^ fB) & 7);
        half8 b = *(const half8*)(slotA + fB * 1024 + s * 16);
        hacc[0] = __builtin_amdgcn_mfma_f32_16x16x32_f16(xfrag[0][kh], b, hacc[0], 0, 0, 0);
        hacc[1] = __builtin_amdgcn_mfma_f32_16x16x32_f16(xfrag[1][kh], b, hacc[1], 0, 0, 0);
      }
      __builtin_amdgcn_s_setprio(0);
      __builtin_amdgcn_s_barrier();                     // all waves done reading slotA
      stage_w1_panel(w1t, eN, f0N, (char*)slotA, w, l); // next w1 panel (8 loads, overlaps gelu)

      // ---- bias + tanh-gelu + route-scale -> hs (rsw bank swizzle) ----
#pragma unroll
      for (int mi = 0; mi < 2; ++mi) {
#pragma unroll
        for (int r = 0; r < 4; ++r) {
          const int m = 32 * mh + 16 * mi + (l >> 4) * 4 + r;
          float v  = hacc[mi][r] + b1v;
          // tanh-gelu: v*E/(E+1), E = exp(1.5957691 v + 0.0713548 v^3); |err| < 4e-4
          float u  = v * (1.5957691f + 0.0713548f * v * v);
          float E  = __expf(u);
          float gl = v * E / (E + 1.0f);
          gl *= routes_lds[ei][m];
          const int sh = (fB >> 3) ^ ((m ^ (m >> 1)) & 7);
          *(_Float16*)(hs + m * 128 + sh * 16 + (fB & 7) * 2) = (_Float16)gl;
        }
      }
      asm volatile("s_waitcnt lgkmcnt(0)" ::: "memory");  // hs writes done before barrier

      // ---- G2: out += gelu(h) @ w2-panel ----
      asm volatile("s_waitcnt vmcnt(8)" ::: "memory");  // w2 panel landed (w1-next in flight)
      __builtin_amdgcn_s_barrier();                     // also publishes hs
      __builtin_amdgcn_s_setprio(1);
      half8 a2[4][2];
#pragma unroll
      for (int mi = 0; mi < 4; ++mi)
#pragma unroll
        for (int kh = 0; kh < 2; ++kh) {
          const int mr = 16 * mi + (l & 15);
          const int sh = (kh * 4 + (l >> 4)) ^ ((mr ^ (mr >> 1)) & 7);
          a2[mi][kh] = *(const half8*)(hs + mr * 128 + sh * 16);
        }
#pragma unroll
      for (int kh = 0; kh < 2; ++kh)
#pragma unroll
        for (int jn = 0; jn < 4; ++jn) {
          const int dB = 64 * dq + 16 * jn + (l & 15);
          const int s  = (kh * 4 + (l >> 4)) ^ (dB & 7);
          half8 b = *(const half8*)(slotB + dB * 128 + s * 16);
#pragma unroll
          for (int mi = 0; mi < 4; ++mi)
            acc[mi][jn] = __builtin_amdgcn_mfma_f32_16x16x32_f16(a2[mi][kh], b, acc[mi][jn], 0, 0, 0);
        }
      __builtin_amdgcn_s_setprio(0);
      __builtin_amdgcn_s_barrier();                     // all waves done reading slotB
      stage_w2_panel(w2t, eN, f0N, (char*)slotB, w, l); // next w2 panel
    }
  }

  asm volatile("s_waitcnt vmcnt(0)" ::: "memory");      // drain tail prefetches

  // ---- epilogue: += sum_e route*b2, then 2-way atomic accumulate ----
#pragma unroll
  for (int jn = 0; jn < 4; ++jn) {
    const int dcol = 64 * dq + 16 * jn + (l & 15);
    float b2v[4];
#pragma unroll
    for (int ei = 0; ei < 4; ++ei) b2v[ei] = b2[(size_t)(eb + ei) * D_MODEL + dcol];
#pragma unroll
    for (int mi = 0; mi < 4; ++mi)
#pragma unroll
      for (int r = 0; r < 4; ++r) {
        const int m = 16 * mi + (l >> 4) * 4 + r;
        float add = 0.f;
#pragma unroll
        for (int ei = 0; ei < 4; ++ei) add += routes_lds[ei][m] * b2v[ei];
        unsafeAtomicAdd(out + (size_t)(m0 + m) * D_MODEL + dcol, acc[mi][jn][r] + add);
      }
  }
}

extern "C" void kernel_launch(void* const* d_in, const int* in_sizes, int n_in,
                              void* d_out, int out_size, void* d_ws, size_t ws_size,
                              hipStream_t stream) {
  (void)in_sizes; (void)n_in; (void)out_size; (void)ws_size;
  const float* x  = (const float*)d_in[0];
  const float* w1 = (const float*)d_in[1];
  const float* b1 = (const float*)d_in[2];
  const float* w2 = (const float*)d_in[3];
  const float* b2 = (const float*)d_in[4];
  const float* wr = (const float*)d_in[5];
  const float* br = (const float*)d_in[6];
  float* out   = (float*)d_out;
  float* route = out + (size_t)N_TOK * D_MODEL;   // output 1 lives in d_out tail

  char* ws = (char*)d_ws;
  _Float16* xb  = (_Float16*)ws;                                           // 8 MiB
  _Float16* w1t = (_Float16*)(ws + (size_t)N_TOK * D_MODEL * 2);           // +16 MiB  [E][F][D]
  _Float16* w2t = (_Float16*)(ws + (size_t)N_TOK * D_MODEL * 2
                                 + (size_t)N_EXP * D_FF * D_MODEL * 2);    // +16 MiB  [E][D][F]

  hipMemsetAsync(out, 0, (size_t)N_TOK * D_MODEL * sizeof(float), stream);
  cvt_x_kernel<<<(N_TOK * D_MODEL / 8) / 256, 256, 0, stream>>>(x, xb);
  transpose_cvt_kernel<<<dim3(D_FF / 32, D_MODEL / 32, N_EXP), 256, 0, stream>>>(w1, w1t, D_MODEL, D_FF);
  transpose_cvt_kernel<<<dim3(D_MODEL / 32, D_FF / 32, N_EXP), 256, 0, stream>>>(w2, w2t, D_FF, D_MODEL);
  router_kernel<<<N_TOK / 4, 256, 0, stream>>>(x, wr, br, route);
  moe_main_kernel<<<dim3(N_TOK / BM, 2), 512, 0, stream>>>(xb, w1t, w2t, b1, b2, route, out);
}